// Round 5
// baseline (1022.852 us; speedup 1.0000x reference)
//
#include <hip/hip_runtime.h>
#include <cmath>
#include <cstdint>

// ---------------------------------------------------------------------------
// MemoryPlus: q = x@w_q^T; sims = norm(q)@norm(keys)^T; top-32 + softmax;
// mem_out = sum_k w_k * values[idx_k]; out = (mem_out * silu(x@w_gate^T)) @ w_out^T
//
// R4->R5 (sims_coarse only, rest unchanged):
//  (a) __launch_bounds__(256,4) had capped arch VGPRs at 64 (R4 VGPR_Count=64
//      vs R3's 124 for the same core) -> scratch spills in the K-loop =
//      the 1.13 GB/dispatch WRITE_SIZE + inflated FETCH. Now (256,2).
//  (b) M=256 rows/block (acc 8x4 MFMA tiles = 128 VGPRs, fits the 256
//      budget): kh re-reads 32x->16x (537->268 MB), MFMA:ds_read per k-step
//      32:12 (was 16:8). Grid (32,16)=512 blocks = exactly 2/CU.
// ---------------------------------------------------------------------------

typedef unsigned short ushort_t;
typedef __bf16 bf16x8 __attribute__((ext_vector_type(8)));
typedef float floatx4 __attribute__((ext_vector_type(4)));

#define TAU 0.16f
#define CAP 512

__device__ __forceinline__ float wave_sum(float v) {
#pragma unroll
  for (int o = 32; o > 0; o >>= 1) v += __shfl_xor(v, o, 64);
  return v;
}

__device__ __forceinline__ unsigned long long pack_vi(float v, int idx) {
  const unsigned int b = __float_as_uint(v);
  const unsigned int fk = (b & 0x80000000u) ? ~b : (b | 0x80000000u);
  return ((unsigned long long)fk << 32) | (unsigned int)(~idx);
}
__device__ __forceinline__ float unpack_v(unsigned long long k) {
  const unsigned int fk = (unsigned int)(k >> 32);
  const unsigned int b = (fk & 0x80000000u) ? (fk & 0x7FFFFFFFu) : ~fk;
  return __uint_as_float(b);
}
__device__ __forceinline__ int unpack_i(unsigned long long k) {
  return ~(int)(unsigned int)(k & 0xFFFFFFFFu);
}

__device__ __forceinline__ ushort_t f2bf_rne(float f) {
  const unsigned int u = __float_as_uint(f);
  return (ushort_t)((u + 0x7FFFu + ((u >> 16) & 1u)) >> 16);
}

__global__ __launch_bounds__(256) void zero_kernel(int* __restrict__ p) {
  p[blockIdx.x * 256 + threadIdx.x] = 0;
}

// inverse L2 norm of each 256-float row (matches F.normalize: 1/max(||v||,1e-12))
__global__ __launch_bounds__(256) void rownorm_inv_kernel(const float* __restrict__ rows,
                                                          float* __restrict__ inv) {
  const int r = blockIdx.x * 4 + (threadIdx.x >> 6);
  const int lane = threadIdx.x & 63;
  const float4 v = ((const float4*)(rows + (long)r * 256))[lane];
  float s = v.x * v.x + v.y * v.y + v.z * v.z + v.w * v.w;
  s = wave_sum(s);
  if (lane == 0) inv[r] = 1.0f / fmaxf(sqrtf(s), 1e-12f);
}

// out_bf16[r][c] = bf16(rows[r][c] * inv[r]), rows of 256. One float4 per thread.
__global__ __launch_bounds__(256) void cast_norm_kernel(const float* __restrict__ rows,
                                                        const float* __restrict__ inv,
                                                        ushort_t* __restrict__ out) {
  const long idx = (long)blockIdx.x * 256 + threadIdx.x;  // float4 index
  const int r = (int)(idx >> 6);
  const float s = inv[r];
  const float4 v = ((const float4*)rows)[idx];
  ushort4 o;
  o.x = f2bf_rne(v.x * s); o.y = f2bf_rne(v.y * s);
  o.z = f2bf_rne(v.z * s); o.w = f2bf_rne(v.w * s);
  ((ushort4*)out)[idx] = o;
}

// plain fp32 -> bf16 cast, one float4 per thread
__global__ __launch_bounds__(256) void cast_bf16_kernel(const float* __restrict__ in,
                                                        ushort_t* __restrict__ out) {
  const long idx = (long)blockIdx.x * 256 + threadIdx.x;
  const float4 v = ((const float4*)in)[idx];
  ushort4 o;
  o.x = f2bf_rne(v.x); o.y = f2bf_rne(v.y);
  o.z = f2bf_rne(v.z); o.w = f2bf_rne(v.w);
  ((ushort4*)out)[idx] = o;
}

// fp32 q GEMM: C[4096,256] = A[4096,1024] @ B[256,1024]^T. 64x64 tile,
// 4x4/thread, BK=32. grid (4,64)=256 blocks (q feeds exact rescore: fp32).
__global__ __launch_bounds__(256) void qgemm_kernel(const float* __restrict__ A,
                                                    const float* __restrict__ B,
                                                    float* __restrict__ C) {
  __shared__ float As[32][64];
  __shared__ float Bs[32][64];
  const int t = threadIdx.x;
  const int tx = t & 15, ty = t >> 4;
  const int m0 = blockIdx.y * 64, n0 = blockIdx.x * 64;
  const int lr = t >> 2;          // staged row 0..63 (4 threads/row)
  const int lk = (t & 3) * 8;     // k offset 0,8,16,24
  const float* Ap = A + (long)(m0 + lr) * 1024 + lk;
  const float* Bp = B + (long)(n0 + lr) * 1024 + lk;
  float acc[4][4] = {};
  for (int kc = 0; kc < 1024; kc += 32) {
    const float4 a0 = *(const float4*)(Ap + kc);
    const float4 a1 = *(const float4*)(Ap + kc + 4);
    const float4 b0 = *(const float4*)(Bp + kc);
    const float4 b1 = *(const float4*)(Bp + kc + 4);
    __syncthreads();
    As[lk + 0][lr] = a0.x; As[lk + 1][lr] = a0.y; As[lk + 2][lr] = a0.z; As[lk + 3][lr] = a0.w;
    As[lk + 4][lr] = a1.x; As[lk + 5][lr] = a1.y; As[lk + 6][lr] = a1.z; As[lk + 7][lr] = a1.w;
    Bs[lk + 0][lr] = b0.x; Bs[lk + 1][lr] = b0.y; Bs[lk + 2][lr] = b0.z; Bs[lk + 3][lr] = b0.w;
    Bs[lk + 4][lr] = b1.x; Bs[lk + 5][lr] = b1.y; Bs[lk + 6][lr] = b1.z; Bs[lk + 7][lr] = b1.w;
    __syncthreads();
#pragma unroll
    for (int kk = 0; kk < 32; kk++) {
      const float4 a = *(const float4*)&As[kk][ty * 4];
      const float4 b = *(const float4*)&Bs[kk][tx * 4];
      const float av[4] = {a.x, a.y, a.z, a.w};
      const float bv[4] = {b.x, b.y, b.z, b.w};
#pragma unroll
      for (int i = 0; i < 4; i++)
#pragma unroll
        for (int j = 0; j < 4; j++) acc[i][j] = fmaf(av[i], bv[j], acc[i][j]);
    }
  }
#pragma unroll
  for (int i = 0; i < 4; i++) {
    float* Cr = C + (long)(m0 + ty * 4 + i) * 256 + n0 + tx * 4;
    *(float4*)Cr = make_float4(acc[i][0], acc[i][1], acc[i][2], acc[i][3]);
  }
}

// bf16 MFMA GEMM: C[M,N] fp32 = A[M,K]bf16 @ B[N,K]bf16^T. 128x128 tile,
// 4 waves each 64x64 (4x4 of 16x16x32), BK=64, register-prefetch pipeline.
template <int EP>  // 0 = none, 1 = silu
__global__ __launch_bounds__(256, 2) void hgemm_bt_kernel(const ushort_t* __restrict__ A,
                                                          const ushort_t* __restrict__ B,
                                                          float* __restrict__ C,
                                                          int M, int N, int K) {
  __shared__ ushort_t As[128][72];
  __shared__ ushort_t Bs[128][72];
  const int t = threadIdx.x;
  const int m0 = blockIdx.y * 128, n0 = blockIdx.x * 128;
  const int lane = t & 63, wv = t >> 6;
  const int wr = wv >> 1, wc = wv & 1;
  const int q4 = lane >> 4, lx = lane & 15;
  const int r0 = t >> 3, sg = t & 7;
  const floatx4 vzero = {0.f, 0.f, 0.f, 0.f};
  floatx4 acc[4][4];
#pragma unroll
  for (int i = 0; i < 4; i++)
#pragma unroll
    for (int j = 0; j < 4; j++) acc[i][j] = vzero;

  uint4 pa[4], pb[4];
#pragma unroll
  for (int it = 0; it < 4; it++) {
    const int row = it * 32 + r0;
    pa[it] = *(const uint4*)(A + (long)(m0 + row) * K + sg * 8);
    pb[it] = *(const uint4*)(B + (long)(n0 + row) * K + sg * 8);
  }
  const int NC = K >> 6;
  for (int c = 0; c < NC; ++c) {
    __syncthreads();
#pragma unroll
    for (int it = 0; it < 4; it++) {
      const int row = it * 32 + r0;
      *(uint4*)&As[row][sg * 8] = pa[it];
      *(uint4*)&Bs[row][sg * 8] = pb[it];
    }
    if (c + 1 < NC) {
      const int c0 = (c + 1) * 64;
#pragma unroll
      for (int it = 0; it < 4; it++) {
        const int row = it * 32 + r0;
        pa[it] = *(const uint4*)(A + (long)(m0 + row) * K + c0 + sg * 8);
        pb[it] = *(const uint4*)(B + (long)(n0 + row) * K + c0 + sg * 8);
      }
    }
    __syncthreads();
#pragma unroll
    for (int ks = 0; ks < 2; ++ks) {
      bf16x8 af[4], bfr[4];
#pragma unroll
      for (int i = 0; i < 4; i++)
        af[i] = *(const bf16x8*)&As[wr * 64 + i * 16 + lx][ks * 32 + q4 * 8];
#pragma unroll
      for (int j = 0; j < 4; j++)
        bfr[j] = *(const bf16x8*)&Bs[wc * 64 + j * 16 + lx][ks * 32 + q4 * 8];
#pragma unroll
      for (int i = 0; i < 4; i++)
#pragma unroll
        for (int j = 0; j < 4; j++)
          acc[i][j] = __builtin_amdgcn_mfma_f32_16x16x32_bf16(af[i], bfr[j], acc[i][j], 0, 0, 0);
    }
  }
#pragma unroll
  for (int i = 0; i < 4; i++)
#pragma unroll
    for (int j = 0; j < 4; j++) {
      const int col = n0 + wc * 64 + j * 16 + lx;
#pragma unroll
      for (int r = 0; r < 4; r++) {
        const int row = m0 + wr * 64 + i * 16 + q4 * 4 + r;
        float v = acc[i][j][r];
        if (EP == 1) v = v / (1.0f + expf(-v));  // silu
        C[(long)row * N + col] = v;
      }
    }
}

// ---------------------------------------------------------------------------
// Coarse sims: bf16 MFMA GEMM, block = 256 q-rows x 1024 keys (8 tiles of
// 256x128), K=256 in 4 chunks of 64, register-prefetch. Each wave covers
// 128 rows x 64 cols (8x4 grid of 16x16x32 MFMAs). After each tile, each
// thread appends acc values > TAU as packed u32 (fp32 top 17 bits | idx) to a
// per-row global candidate list. No barriers/LDS for selection.
// ---------------------------------------------------------------------------
__global__ __launch_bounds__(256, 2) void sims_coarse_kernel(const ushort_t* __restrict__ qh,
                                                             const ushort_t* __restrict__ kh,
                                                             int* __restrict__ cnt,
                                                             unsigned int* __restrict__ cand) {
  __shared__ ushort_t As[256][72];
  __shared__ ushort_t Bs[128][72];
  const int t = threadIdx.x;
  const int cs = blockIdx.x, rb = blockIdx.y;
  const int m0 = rb * 256;
  const int lane = t & 63, wv = t >> 6;
  const int wr = wv >> 1, wc = wv & 1;
  const int q4 = lane >> 4, lx = lane & 15;
  const int r0 = t >> 3, sg = t & 7;

  uint4 pa[8], pb[4];
  {
    const int n0 = cs * 1024;
#pragma unroll
    for (int it = 0; it < 8; it++)
      pa[it] = *(const uint4*)(qh + (long)(m0 + it * 32 + r0) * 256 + sg * 8);
#pragma unroll
    for (int it = 0; it < 4; it++)
      pb[it] = *(const uint4*)(kh + (long)(n0 + it * 32 + r0) * 256 + sg * 8);
  }

  for (int tile = 0; tile < 8; ++tile) {
    const int n0 = cs * 1024 + tile * 128;
    const floatx4 vzero = {0.f, 0.f, 0.f, 0.f};
    floatx4 acc[8][4];
#pragma unroll
    for (int i = 0; i < 8; i++)
#pragma unroll
      for (int j = 0; j < 4; j++) acc[i][j] = vzero;

    for (int chunk = 0; chunk < 4; ++chunk) {
      __syncthreads();
#pragma unroll
      for (int it = 0; it < 8; it++)
        *(uint4*)&As[it * 32 + r0][sg * 8] = pa[it];
#pragma unroll
      for (int it = 0; it < 4; it++)
        *(uint4*)&Bs[it * 32 + r0][sg * 8] = pb[it];
      int nc = chunk + 1, nt = tile;
      if (nc == 4) { nc = 0; nt = tile + 1; }
      if (nt < 8) {
        const int nn0 = cs * 1024 + nt * 128;
        const int c0 = nc * 64;
#pragma unroll
        for (int it = 0; it < 8; it++)
          pa[it] = *(const uint4*)(qh + (long)(m0 + it * 32 + r0) * 256 + c0 + sg * 8);
#pragma unroll
        for (int it = 0; it < 4; it++)
          pb[it] = *(const uint4*)(kh + (long)(nn0 + it * 32 + r0) * 256 + c0 + sg * 8);
      }
      __syncthreads();
#pragma unroll
      for (int ks = 0; ks < 2; ++ks) {
        bf16x8 af[8], bfr[4];
#pragma unroll
        for (int j = 0; j < 4; j++)
          bfr[j] = *(const bf16x8*)&Bs[wc * 64 + j * 16 + lx][ks * 32 + q4 * 8];
#pragma unroll
        for (int i = 0; i < 8; i++)
          af[i] = *(const bf16x8*)&As[wr * 128 + i * 16 + lx][ks * 32 + q4 * 8];
#pragma unroll
        for (int i = 0; i < 8; i++)
#pragma unroll
          for (int j = 0; j < 4; j++)
            acc[i][j] = __builtin_amdgcn_mfma_f32_16x16x32_bf16(af[i], bfr[j], acc[i][j], 0, 0, 0);
      }
    }

    // threshold scan + global append (rare: ~0.5% of values pass)
#pragma unroll
    for (int i = 0; i < 8; i++)
#pragma unroll
      for (int j = 0; j < 4; j++)
#pragma unroll
        for (int r = 0; r < 4; r++) {
          const float v = acc[i][j][r];
          if (v > TAU) {
            const int row = m0 + wr * 128 + i * 16 + q4 * 4 + r;
            const int idx = n0 + wc * 64 + j * 16 + lx;
            const int slot = atomicAdd(&cnt[row], 1);
            if (slot < CAP)
              cand[(long)row * CAP + slot] =
                  (__float_as_uint(v) & 0xFFFF8000u) | (unsigned int)idx;
          }
        }
  }
}

// ---------------------------------------------------------------------------
// Refine: one wave per row. Coarse top-48 of the candidate list (monotone u32
// keys), exact fp32 rescore vs original keys, exact top-32 (jax tie-break:
// value desc then idx asc), softmax.
// ---------------------------------------------------------------------------
__global__ __launch_bounds__(256) void refine_kernel(const float* __restrict__ q,
                                                     const float* __restrict__ qinv,
                                                     const float* __restrict__ keys,
                                                     const float* __restrict__ kinv,
                                                     const int* __restrict__ cnt,
                                                     const unsigned int* __restrict__ cand,
                                                     float* __restrict__ w_top,
                                                     int* __restrict__ i_top) {
  const int row = blockIdx.x * 4 + (threadIdx.x >> 6);
  const int lane = threadIdx.x & 63;
  // q-hat fragment (4 k-dims per lane), same elementwise values as numpy's q_norm
  const float qs = qinv[row];
  float4 qh = ((const float4*)(q + (long)row * 256))[lane];
  qh.x *= qs; qh.y *= qs; qh.z *= qs; qh.w *= qs;
  int ncand = cnt[row];
  if (ncand > CAP) ncand = CAP;
  unsigned int loc[8];
#pragma unroll
  for (int s = 0; s < 8; s++) {
    const int c = s * 64 + lane;
    loc[s] = (c < ncand) ? cand[(long)row * CAP + c] : 0u;
  }
  // coarse top-48 by u32 key (monotone in bf16 sim; ties resolved by rescore)
  unsigned int mykey = 0;
  for (int it = 0; it < 48; ++it) {
    unsigned int best = loc[0];
#pragma unroll
    for (int s = 1; s < 8; s++) best = (loc[s] > best) ? loc[s] : best;
#pragma unroll
    for (int o = 32; o > 0; o >>= 1) {
      const unsigned int oth = __shfl_xor(best, o, 64);
      if (oth > best) best = oth;
    }
    if (best == 0u) break;  // wave-uniform: list exhausted
#pragma unroll
    for (int s = 0; s < 8; s++)
      if (loc[s] == best) loc[s] = 0;  // keys unique per row
    if (lane == it) mykey = best;
  }
  const int myidx = (int)(mykey & 0x7FFFu);
  // exact fp32 rescore of the (up to) 48
  float myexact = 0.0f;
  for (int c = 0; c < 48; ++c) {
    const unsigned int ky = __shfl(mykey, c, 64);
    if (ky == 0u) continue;  // wave-uniform branch
    const int idx = (int)(ky & 0x7FFFu);
    const float4 kv = ((const float4*)(keys + (long)idx * 256))[lane];
    float d = qh.x * kv.x + qh.y * kv.y + qh.z * kv.z + qh.w * kv.w;
    d = wave_sum(d);
    const float sim = d * kinv[idx];
    if (lane == c) myexact = sim;
  }
  // exact top-32 with jax tie-break (value desc, idx asc)
  unsigned long long ekey = (lane < 48 && mykey != 0u) ? pack_vi(myexact, myidx) : 0ULL;
  unsigned long long sel = 0;
  float maxv = 0.0f;
  for (int it = 0; it < 32; ++it) {
    unsigned long long best = ekey;
#pragma unroll
    for (int o = 32; o > 0; o >>= 1) {
      const unsigned long long oth = __shfl_xor(best, o, 64);
      if (oth > best) best = oth;
    }
    if (ekey == best) ekey = 0;
    if (lane == it) sel = best;
    if (it == 0) maxv = unpack_v(best);
  }
  float e = 0.0f;
  int oidx = 0;
  if (lane < 32) {
    e = expf(unpack_v(sel) - maxv);
    oidx = unpack_i(sel);
  }
  const float ssum = wave_sum(e);
  if (lane < 32) {
    w_top[(long)row * 32 + lane] = e / ssum;
    i_top[(long)row * 32 + lane] = oidx;
  }
}

// mem_out = sum_k w_k * values[idx_k]; h = bf16(mem_out * gate). One block/row.
__global__ __launch_bounds__(256) void gather_gate_kernel(const float* __restrict__ values,
                                                          const float* __restrict__ w_top,
                                                          const int* __restrict__ i_top,
                                                          const float* __restrict__ gate,
                                                          ushort_t* __restrict__ h) {
  __shared__ float w[32];
  __shared__ int ix[32];
  const int row = blockIdx.x;
  const int t = threadIdx.x;
  if (t < 32) {
    w[t] = w_top[(long)row * 32 + t];
    ix[t] = i_top[(long)row * 32 + t];
  }
  __syncthreads();
  float4 acc = make_float4(0.f, 0.f, 0.f, 0.f);
#pragma unroll 4
  for (int k = 0; k < 32; k++) {
    const float4 v = *(const float4*)(values + (long)ix[k] * 1024 + t * 4);
    const float wk = w[k];
    acc.x = fmaf(wk, v.x, acc.x);
    acc.y = fmaf(wk, v.y, acc.y);
    acc.z = fmaf(wk, v.z, acc.z);
    acc.w = fmaf(wk, v.w, acc.w);
  }
  const float4 g = *(const float4*)(gate + (long)row * 1024 + t * 4);
  ushort4 o;
  o.x = f2bf_rne(acc.x * g.x); o.y = f2bf_rne(acc.y * g.y);
  o.z = f2bf_rne(acc.z * g.z); o.w = f2bf_rne(acc.w * g.w);
  ((ushort4*)(h + (long)row * 1024))[t] = o;
}

extern "C" void kernel_launch(void* const* d_in, const int* in_sizes, int n_in,
                              void* d_out, int out_size, void* d_ws, size_t ws_size,
                              hipStream_t stream) {
  const float* x      = (const float*)d_in[0];  // [4,1024,1024]
  const float* keys   = (const float*)d_in[1];  // [32768,256]
  const float* values = (const float*)d_in[2];  // [32768,1024]
  const float* w_q    = (const float*)d_in[3];  // [256,1024]
  const float* w_gate = (const float*)d_in[4];  // [1024,1024]
  const float* w_out  = (const float*)d_in[5];  // [1024,1024]
  float* out = (float*)d_out;                   // [4,1024,1024]

  // workspace layout (4-byte units), ~51.5 MB total
  float* q        = (float*)d_ws;                   // 1,048,576
  float* qinv     = q + 1048576;                    // 4096
  float* kinv     = qinv + 4096;                    // 32768
  int*   cnt      = (int*)(kinv + 32768);           // 4096
  float* w_top    = (float*)(cnt + 4096);           // 131072
  int*   i_top    = (int*)(w_top + 131072);         // 131072
  ushort_t* qh    = (ushort_t*)(i_top + 131072);    // 524,288 f
  float* khf      = (float*)(qh + 1048576);         // 4,194,304 f region
  ushort_t* kh    = (ushort_t*)khf;                 //   [cast -> sims]
  ushort_t* hbf   = (ushort_t*)khf;                 //   alias: h bf16 [gather -> out GEMM]
  ushort_t* wo    = (ushort_t*)(khf + 2097152);     //   alias: w_out bf16 [after sims]
  float* gate     = khf + 4194304;                  // 4,194,304 f
  float* xbfr     = gate + 4194304;                 // 2,097,152 f region
  ushort_t* xb    = (ushort_t*)xbfr;                //   x bf16 [cast -> gate GEMM]
  unsigned int* cand = (unsigned int*)xbfr;         //   alias: candidates [sims -> refine]
  ushort_t* wg    = (ushort_t*)(xbfr + 2097152);    // 524,288 f

  zero_kernel<<<dim3(16), 256, 0, stream>>>(cnt);
  qgemm_kernel<<<dim3(4, 64), 256, 0, stream>>>(x, w_q, q);
  rownorm_inv_kernel<<<dim3(32768 / 4), 256, 0, stream>>>(keys, kinv);
  rownorm_inv_kernel<<<dim3(4096 / 4), 256, 0, stream>>>(q, qinv);
  cast_norm_kernel<<<dim3(4096 * 64 / 256), 256, 0, stream>>>(q, qinv, qh);
  cast_norm_kernel<<<dim3(32768 * 64 / 256), 256, 0, stream>>>(keys, kinv, kh);
  cast_bf16_kernel<<<dim3(4096), 256, 0, stream>>>(x, xb);
  cast_bf16_kernel<<<dim3(1024), 256, 0, stream>>>(w_gate, wg);
  // gate GEMM must precede sims (cand aliases xb)
  hgemm_bt_kernel<1><<<dim3(8, 32), 256, 0, stream>>>(xb, wg, gate, 4096, 1024, 1024);
  sims_coarse_kernel<<<dim3(32, 16), 256, 0, stream>>>(qh, kh, cnt, cand);
  // w_out cast must follow sims (wo aliases kh region)
  cast_bf16_kernel<<<dim3(1024), 256, 0, stream>>>(w_out, wo);
  refine_kernel<<<dim3(4096 / 4), 256, 0, stream>>>(q, qinv, keys, kinv, cnt, cand, w_top, i_top);
  gather_gate_kernel<<<dim3(4096), 256, 0, stream>>>(values, w_top, i_top, gate, hbf);
  hgemm_bt_kernel<0><<<dim3(8, 32), 256, 0, stream>>>(hbf, wo, out, 4096, 1024, 1024);
}